// Round 11
// baseline (448.185 us; speedup 1.0000x reference)
//
#include <hip/hip_runtime.h>
#include <stdint.h>

typedef short bf16x8 __attribute__((ext_vector_type(8)));
typedef float f32x4 __attribute__((ext_vector_type(4)));
typedef unsigned short us4 __attribute__((ext_vector_type(4)));
typedef unsigned short us8 __attribute__((ext_vector_type(8)));
typedef unsigned uint2v __attribute__((ext_vector_type(2)));

#define SCL 0.18033688011112042f  /* log2(e)/sqrt(64) */

__device__ __forceinline__ unsigned short f2bf(float f) {
  union { float f; unsigned u; } v; v.f = f;
  unsigned r = v.u + 0x7fffu + ((v.u >> 16) & 1u);
  return (unsigned short)(r >> 16);
}

__device__ __forceinline__ unsigned cvtpk(float lo, float hi) {
  unsigned r;
  asm("v_cvt_pk_bf16_f32 %0, %1, %2" : "=v"(r) : "v"(lo), "v"(hi));
  return r;
}

__device__ __forceinline__ float bf2f(unsigned short h) {
  union { unsigned u; float f; } v; v.u = ((unsigned)h) << 16; return v.f;
}

#define GL2LDS(g, l) __builtin_amdgcn_global_load_lds( \
    (const __attribute__((address_space(1))) void*)(g), \
    (__attribute__((address_space(3))) void*)(l), 16, 0, 0)

// ---------------- kernel 1: f32 -> bf16 conversion ----------------
__global__ __launch_bounds__(256) void convert_all(
    const float* __restrict__ q, const float* __restrict__ k, const float* __restrict__ v,
    const float* __restrict__ wq, const float* __restrict__ wk, const float* __restrict__ wv,
    const float* __restrict__ wo,
    unsigned short* __restrict__ qb, unsigned short* __restrict__ kb, unsigned short* __restrict__ vb,
    unsigned short* __restrict__ wqb, unsigned short* __restrict__ wkb, unsigned short* __restrict__ wvb,
    unsigned short* __restrict__ wob)
{
  const long NB = 8388608, NW = 1048576;
  long i = ((long)blockIdx.x * 256 + threadIdx.x) * 4;
  if (i >= 3*NB + 4*NW) return;
  const float* src; unsigned short* dst; long off;
  if (i < NB)              { src = q;  dst = qb;  off = i; }
  else if (i < 2*NB)       { src = k;  dst = kb;  off = i - NB; }
  else if (i < 3*NB)       { src = v;  dst = vb;  off = i - 2*NB; }
  else if (i < 3*NB+NW)    { src = wq; dst = wqb; off = i - 3*NB; }
  else if (i < 3*NB+2*NW)  { src = wk; dst = wkb; off = i - 3*NB - NW; }
  else if (i < 3*NB+3*NW)  { src = wv; dst = wvb; off = i - 3*NB - 2*NW; }
  else                     { src = wo; dst = wob; off = i - 3*NB - 3*NW; }
  float4 x = *(const float4*)(src + off);
  us4 o; o.x = f2bf(x.x); o.y = f2bf(x.y); o.z = f2bf(x.z); o.w = f2bf(x.w);
  *(us4*)(dst + off) = o;
}

// ---------------- kernel 2: QKV projection GEMM (2-phase dbuf, LDS-coalesced epilogue) ----------------
// z=0 -> qh (PRE-SCALED by SCL), z=1 -> kh, z=2 -> vt (transposed per head)
__global__ __launch_bounds__(256, 2) void qkv_gemm(
    const unsigned short* __restrict__ qb, const unsigned short* __restrict__ kb,
    const unsigned short* __restrict__ vb,
    const unsigned short* __restrict__ wqb, const unsigned short* __restrict__ wkb,
    const unsigned short* __restrict__ wvb,
    const float* __restrict__ bq, const float* __restrict__ bk, const float* __restrict__ bv,
    unsigned short* __restrict__ qh, unsigned short* __restrict__ kh,
    unsigned short* __restrict__ vt)
{
  const int z = blockIdx.z;
  const unsigned short* X = (z == 0) ? qb : (z == 1) ? kb : vb;
  const unsigned short* W = (z == 0) ? wqb : (z == 1) ? wkb : wvb;
  const float* bias = (z == 0) ? bq : (z == 1) ? bk : bv;
  unsigned short* dqh = (z == 0) ? qh : kh;
  const float sc = (z == 0) ? SCL : 1.0f;

  const int flat = blockIdx.x + (blockIdx.y << 6);
  const int xcd = flat & 7, ii = flat >> 3;
  const int m0 = (xcd * 8 + (ii & 7)) * 128;
  const int n0 = (ii >> 3) * 128;

  const int tid = threadIdx.x, lane = tid & 63, w = tid >> 6;
  const int wr = w >> 1, wc = w & 1;
  const int lg = lane >> 4, ll = lane & 15;

  __shared__ __align__(16) char smem_q[32768];
  unsigned short* As = (unsigned short*)smem_q;             // [2][128][32]
  unsigned short* Bs = (unsigned short*)(smem_q + 16384);   // [2][128][32]
  unsigned short* T  = (unsigned short*)smem_q;             // epilogue overlay [64][130]

  f32x4 acc[4][4] = {};

  const char* gA = (const char*)X + ((size_t)(m0 + w*32 + (lane >> 2)) * 1024) * 2 + (lane & 3) * 16;
  const char* gB = (const char*)W + ((size_t)(n0 + w*32 + (lane >> 2)) * 1024) * 2 + (lane & 3) * 16;

#define STAGE_G(buf) do { \
    char* lA_ = (char*)As + (buf)*8192 + w*2048; \
    char* lB_ = (char*)Bs + (buf)*8192 + w*2048; \
    GL2LDS(gA, lA_); GL2LDS(gA + 32768, lA_ + 1024); \
    GL2LDS(gB, lB_); GL2LDS(gB + 32768, lB_ + 1024); \
    gA += 64; gB += 64; } while (0)

  STAGE_G(0);
  __syncthreads();

  for (int k0 = 0; k0 < 1024; k0 += 32) {
    const int cur = (k0 >> 5) & 1;
    if (k0 < 992) STAGE_G(cur ^ 1);
    const unsigned short* Ac = As + cur * 4096;
    const unsigned short* Bc = Bs + cur * 4096;
    bf16x8 xa[4], wb[4];
    const int kc = lg * 8;
#pragma unroll
    for (int f = 0; f < 4; ++f) xa[f] = *(const bf16x8*)&Ac[(wr*64 + f*16 + ll)*32 + kc];
#pragma unroll
    for (int f = 0; f < 4; ++f) wb[f] = *(const bf16x8*)&Bc[(wc*64 + f*16 + ll)*32 + kc];
    if (z < 2) {
#pragma unroll
      for (int fn = 0; fn < 4; ++fn)
#pragma unroll
        for (int fm = 0; fm < 4; ++fm)
          acc[fn][fm] = __builtin_amdgcn_mfma_f32_16x16x32_bf16(wb[fn], xa[fm], acc[fn][fm], 0, 0, 0);
    } else {
#pragma unroll
      for (int fm = 0; fm < 4; ++fm)
#pragma unroll
        for (int fn = 0; fn < 4; ++fn)
          acc[fm][fn] = __builtin_amdgcn_mfma_f32_16x16x32_bf16(xa[fm], wb[fn], acc[fm][fn], 0, 0, 0);
    }
    __syncthreads();
  }

  if (z < 2) {
    const int b_ = m0 >> 11;
#pragma unroll
    for (int half = 0; half < 2; ++half) {
      __syncthreads();
      if (wr == half) {
#pragma unroll
        for (int fn = 0; fn < 4; ++fn) {
          const int n_l = wc*64 + fn*16 + lg*4;
          const float4 b4 = *(const float4*)&bias[n0 + n_l];
#pragma unroll
          for (int fm = 0; fm < 4; ++fm) {
            us4 pk;
            pk.x = f2bf((acc[fn][fm][0] + b4.x) * sc);
            pk.y = f2bf((acc[fn][fm][1] + b4.y) * sc);
            pk.z = f2bf((acc[fn][fm][2] + b4.z) * sc);
            pk.w = f2bf((acc[fn][fm][3] + b4.w) * sc);
            *(us4*)&T[(fm*16 + ll)*130 + n_l] = pk;
          }
        }
      }
      __syncthreads();
      const int seg = tid >> 3, off = (tid & 7) * 8;
#pragma unroll
      for (int it = 0; it < 4; ++it) {
        const int s = it*32 + seg;
        const int ml = s >> 1, nh = (s & 1) << 6;
        us8 v = *(const us8*)&T[ml*130 + nh + off];
        const int m_g = m0 + half*64 + ml;
        const int l_ = m_g & 2047;
        const int h = (n0 + nh) >> 6;
        *(us8*)&dqh[((size_t)(h*4 + b_)*2048 + l_)*64 + off] = v;
      }
    }
  } else {
    const int b_ = m0 >> 11;
#pragma unroll
    for (int half = 0; half < 2; ++half) {
      __syncthreads();
      if (wc == half) {
#pragma unroll
        for (int fn = 0; fn < 4; ++fn) {
          const float bias_n = bias[n0 + half*64 + fn*16 + ll];
#pragma unroll
          for (int fm = 0; fm < 4; ++fm) {
            us4 pk;
            pk.x = f2bf(acc[fm][fn][0] + bias_n);
            pk.y = f2bf(acc[fm][fn][1] + bias_n);
            pk.z = f2bf(acc[fm][fn][2] + bias_n);
            pk.w = f2bf(acc[fm][fn][3] + bias_n);
            *(us4*)&T[(fn*16 + ll)*130 + wr*64 + fm*16 + lg*4] = pk;
          }
        }
      }
      __syncthreads();
      const int row = tid >> 4, mc = (tid & 15) * 8;
#pragma unroll
      for (int it = 0; it < 4; ++it) {
        const int rr = it*16 + row;
        us8 v = *(const us8*)&T[rr*130 + mc];
        const int n_g = n0 + half*64 + rr;
        const int h = n_g >> 6, dkk = n_g & 63;
        const int l_ = (m0 + mc) & 2047;
        *(us8*)&vt[((size_t)(h*4 + b_)*64 + dkk)*2048 + l_] = v;
      }
    }
  }
}

// ---------------- kernel 3: attention v8 (2 q-tiles/block, liveness-disciplined merge) ----------------
// 512 blocks; per block: P1(a); merged { S_a -> P_a -> S_b(reuse regs) -> PV(a)+stores }; P2(b).
__global__ __launch_bounds__(256, 2) void attn_kernel(
    const unsigned short* __restrict__ qh, const unsigned short* __restrict__ kh,
    const unsigned short* __restrict__ vt, float* __restrict__ probs,
    unsigned short* __restrict__ attn_o)
{
  const int bid = blockIdx.x;
  const int xcd = bid & 7;
  const int idx = bid >> 3;           // 0..63
  const int hb  = xcd * 8 + (idx & 7);
  const int qp  = idx >> 3;           // 0..7
  const int qt_a = qp * 2, qt_b = qp * 2 + 1;

  const int tid = threadIdx.x, lane = tid & 63, w = tid >> 6;
  const int wr = w >> 1, wc = w & 1;
  const int lg = lane >> 4, ll = lane & 15;

  __shared__ __align__(16) char smem[38400];
  unsigned short* Pb = (unsigned short*)smem;        // [2][128][72] bf16 (36864 B)
  float* rs   = (float*)(smem + 36864);              // [2][128]
  float* invl = (float*)(smem + 37888);              // [128]
  float* Ored = (float*)smem;                        // epilogue overlay [2][64][64] (32 KB)

  const size_t slab = (size_t)hb << 17;

  bf16x8 qfa[4][2], qfb[4][2];
#pragma unroll
  for (int fq = 0; fq < 4; ++fq)
#pragma unroll
    for (int dh = 0; dh < 2; ++dh) {
      qfa[fq][dh] = *(const bf16x8*)&qh[slab + (size_t)(qt_a*128 + wr*64 + fq*16 + ll)*64 + dh*32 + lg*8];
      qfb[fq][dh] = *(const bf16x8*)&qh[slab + (size_t)(qt_b*128 + wr*64 + fq*16 + ll)*64 + dh*32 + lg*8];
    }

  const unsigned short* Kf = kh + slab + (size_t)(wc*32 + ll)*64 + lg*8;
  const unsigned short* Vf = vt + slab + (size_t)ll*2048 + wc*32 + lg*8;

  const int prow = tid >> 4, pcol = (tid & 15) * 4;

  // ---- phase 1: P1(a) ----
  float rsum[4] = {0.f, 0.f, 0.f, 0.f};
  for (int kt = 0; kt < 32; ++kt) {
    bf16x8 ka[2][2];
#pragma unroll
    for (int fk = 0; fk < 2; ++fk)
#pragma unroll
      for (int dh = 0; dh < 2; ++dh)
        ka[fk][dh] = *(const bf16x8*)(Kf + kt*4096 + fk*1024 + dh*32);
    f32x4 s[2][4] = {};
    __builtin_amdgcn_s_setprio(1);
#pragma unroll
    for (int dh = 0; dh < 2; ++dh)
#pragma unroll
      for (int fk = 0; fk < 2; ++fk)
#pragma unroll
        for (int fq = 0; fq < 4; ++fq)
          s[fk][fq] = __builtin_amdgcn_mfma_f32_16x16x32_bf16(ka[fk][dh], qfa[fq][dh], s[fk][fq], 0, 0, 0);
    __builtin_amdgcn_s_setprio(0);
#pragma unroll
    for (int fk = 0; fk < 2; ++fk)
#pragma unroll
      for (int fq = 0; fq < 4; ++fq)
#pragma unroll
        for (int r = 0; r < 4; ++r)
          rsum[fq] += exp2f(s[fk][fq][r]);
  }

#pragma unroll
  for (int fq = 0; fq < 4; ++fq) {
    float t = rsum[fq];
    t += __shfl_xor(t, 16);
    t += __shfl_xor(t, 32);
    rsum[fq] = t;
  }
  if (lg == 0) {
#pragma unroll
    for (int fq = 0; fq < 4; ++fq)
      rs[wc*128 + wr*64 + fq*16 + ll] = rsum[fq];
  }
  __syncthreads();
  if (tid < 128) invl[tid] = 1.0f / (rs[tid] + rs[128 + tid]);
  __syncthreads();
  float inv_ra[4];
#pragma unroll
  for (int fq = 0; fq < 4; ++fq) inv_ra[fq] = invl[wr*64 + fq*16 + ll];
  __syncthreads();

  // ---- phase 2: merged — P2(a) with P1(b) piggybacked (register reuse ordering) ----
  f32x4 o[4][4] = {};
  float rsb[4] = {0.f, 0.f, 0.f, 0.f};
  float* pb2a = probs + ((size_t)hb << 22) + (size_t)(qt_a*128) * 2048;

  for (int kt = 0; kt < 32; ++kt) {
    unsigned short* Pc = Pb + (kt & 1) * 9216;
    bf16x8 vb[4];
#pragma unroll
    for (int f = 0; f < 4; ++f)
      vb[f] = *(const bf16x8*)(Vf + f*32768 + kt*64);
    bf16x8 ka[2][2];
#pragma unroll
    for (int fk = 0; fk < 2; ++fk)
#pragma unroll
      for (int dh = 0; dh < 2; ++dh)
        ka[fk][dh] = *(const bf16x8*)(Kf + kt*4096 + fk*1024 + dh*32);

    // S_a -> P_a (s dies at the LDS write)
    {
      f32x4 s[2][4] = {};
      __builtin_amdgcn_s_setprio(1);
#pragma unroll
      for (int dh = 0; dh < 2; ++dh)
#pragma unroll
        for (int fk = 0; fk < 2; ++fk)
#pragma unroll
          for (int fq = 0; fq < 4; ++fq)
            s[fk][fq] = __builtin_amdgcn_mfma_f32_16x16x32_bf16(ka[fk][dh], qfa[fq][dh], s[fk][fq], 0, 0, 0);
      __builtin_amdgcn_s_setprio(0);
#pragma unroll
      for (int fk = 0; fk < 2; ++fk)
#pragma unroll
        for (int fq = 0; fq < 4; ++fq) {
          float p0 = exp2f(s[fk][fq][0]) * inv_ra[fq];
          float p1 = exp2f(s[fk][fq][1]) * inv_ra[fq];
          float p2 = exp2f(s[fk][fq][2]) * inv_ra[fq];
          float p3 = exp2f(s[fk][fq][3]) * inv_ra[fq];
          uint2v u; u.x = cvtpk(p0, p1); u.y = cvtpk(p2, p3);
          *(uint2v*)&Pc[(wr*64 + fq*16 + ll)*72 + wc*32 + fk*16 + lg*4] = u;
        }
    }

    // S_b reusing the freed registers; ka dies here
    {
      f32x4 s[2][4] = {};
      __builtin_amdgcn_s_setprio(1);
#pragma unroll
      for (int dh = 0; dh < 2; ++dh)
#pragma unroll
        for (int fk = 0; fk < 2; ++fk)
#pragma unroll
          for (int fq = 0; fq < 4; ++fq)
            s[fk][fq] = __builtin_amdgcn_mfma_f32_16x16x32_bf16(ka[fk][dh], qfb[fq][dh], s[fk][fq], 0, 0, 0);
      __builtin_amdgcn_s_setprio(0);
#pragma unroll
      for (int fk = 0; fk < 2; ++fk)
#pragma unroll
        for (int fq = 0; fq < 4; ++fq)
#pragma unroll
          for (int r = 0; r < 4; ++r)
            rsb[fq] += exp2f(s[fk][fq][r]);
    }
    __syncthreads();

    // PV(a)
    bf16x8 pa[4];
#pragma unroll
    for (int fm = 0; fm < 4; ++fm)
      pa[fm] = *(const bf16x8*)&Pc[(wr*64 + fm*16 + ll)*72 + wc*32 + lg*8];
    __builtin_amdgcn_s_setprio(1);
#pragma unroll
    for (int fm = 0; fm < 4; ++fm)
#pragma unroll
      for (int fd = 0; fd < 4; ++fd)
        o[fm][fd] = __builtin_amdgcn_mfma_f32_16x16x32_bf16(pa[fm], vb[fd], o[fm][fd], 0, 0, 0);
    __builtin_amdgcn_s_setprio(0);

    // coalesced probs store (a)
    float* pdst = pb2a + kt*64;
#pragma unroll
    for (int j = 0; j < 8; ++j) {
      const int row = j*16 + prow;
      us4 pv = *(const us4*)&Pc[row*72 + pcol];
      f32x4 pf; pf[0] = bf2f(pv.x); pf[1] = bf2f(pv.y); pf[2] = bf2f(pv.z); pf[3] = bf2f(pv.w);
      __builtin_nontemporal_store(pf, (f32x4*)(pdst + (size_t)row*2048 + pcol));
    }
  }

  // ---- tile-b rowsum reduce + tile-a O epilogue ----
  __syncthreads();
#pragma unroll
  for (int fq = 0; fq < 4; ++fq) {
    float t = rsb[fq];
    t += __shfl_xor(t, 16);
    t += __shfl_xor(t, 32);
    rsb[fq] = t;
  }
  if (lg == 0) {
#pragma unroll
    for (int fq = 0; fq < 4; ++fq)
      rs[wc*128 + wr*64 + fq*16 + ll] = rsb[fq];
  }
  if (wc == 1) {
#pragma unroll
    for (int fm = 0; fm < 4; ++fm)
#pragma unroll
      for (int fd = 0; fd < 4; ++fd)
#pragma unroll
        for (int r = 0; r < 4; ++r)
          Ored[wr*4096 + (fm*16 + lg*4 + r)*64 + fd*16 + ll] = o[fm][fd][r];
  }
  __syncthreads();
  if (tid < 128) invl[tid] = 1.0f / (rs[tid] + rs[128 + tid]);
  if (wc == 0) {
    const int b_ = hb & 3, h = hb >> 2;
#pragma unroll
    for (int fm = 0; fm < 4; ++fm)
#pragma unroll
      for (int fd = 0; fd < 4; ++fd)
#pragma unroll
        for (int r = 0; r < 4; ++r) {
          const int qrow = fm*16 + lg*4 + r;
          const int d = fd*16 + ll;
          float val = o[fm][fd][r] + Ored[wr*4096 + qrow*64 + d];
          const int mg = b_*2048 + qt_a*128 + wr*64 + qrow;
          attn_o[(size_t)mg*1024 + h*64 + d] = f2bf(val);
        }
  }
  __syncthreads();
  float inv_rb[4];
#pragma unroll
  for (int fq = 0; fq < 4; ++fq) inv_rb[fq] = invl[wr*64 + fq*16 + ll];
  __syncthreads();

  // ---- phase 3: P2(b) ----
#pragma unroll
  for (int fm = 0; fm < 4; ++fm)
#pragma unroll
    for (int fd = 0; fd < 4; ++fd)
      o[fm][fd] = f32x4{0.f, 0.f, 0.f, 0.f};
  float* pb2b = probs + ((size_t)hb << 22) + (size_t)(qt_b*128) * 2048;

  for (int kt = 0; kt < 32; ++kt) {
    unsigned short* Pc = Pb + (kt & 1) * 9216;
    bf16x8 vb[4];
#pragma unroll
    for (int f = 0; f < 4; ++f)
      vb[f] = *(const bf16x8*)(Vf + f*32768 + kt*64);
    bf16x8 ka[2][2];
#pragma unroll
    for (int fk = 0; fk < 2; ++fk)
#pragma unroll
      for (int dh = 0; dh < 2; ++dh)
        ka[fk][dh] = *(const bf16x8*)(Kf + kt*4096 + fk*1024 + dh*32);

    f32x4 s[2][4] = {};
    __builtin_amdgcn_s_setprio(1);
#pragma unroll
    for (int dh = 0; dh < 2; ++dh)
#pragma unroll
      for (int fk = 0; fk < 2; ++fk)
#pragma unroll
        for (int fq = 0; fq < 4; ++fq)
          s[fk][fq] = __builtin_amdgcn_mfma_f32_16x16x32_bf16(ka[fk][dh], qfb[fq][dh], s[fk][fq], 0, 0, 0);
    __builtin_amdgcn_s_setprio(0);

#pragma unroll
    for (int fk = 0; fk < 2; ++fk)
#pragma unroll
      for (int fq = 0; fq < 4; ++fq) {
        float p0 = exp2f(s[fk][fq][0]) * inv_rb[fq];
        float p1 = exp2f(s[fk][fq][1]) * inv_rb[fq];
        float p2 = exp2f(s[fk][fq][2]) * inv_rb[fq];
        float p3 = exp2f(s[fk][fq][3]) * inv_rb[fq];
        uint2v u; u.x = cvtpk(p0, p1); u.y = cvtpk(p2, p3);
        *(uint2v*)&Pc[(wr*64 + fq*16 + ll)*72 + wc*32 + fk*16 + lg*4] = u;
      }
    __syncthreads();

    bf16x8 pa[4];
#pragma unroll
    for (int fm = 0; fm < 4; ++fm)
      pa[fm] = *(const bf16x8*)&Pc[(wr*64 + fm*16 + ll)*72 + wc*32 + lg*8];
    __builtin_amdgcn_s_setprio(1);
#pragma unroll
    for (int fm = 0; fm < 4; ++fm)
#pragma unroll
      for (int fd = 0; fd < 4; ++fd)
        o[fm][fd] = __builtin_amdgcn_mfma_f32_16x16x32_bf16(pa[fm], vb[fd], o[fm][fd], 0, 0, 0);
    __builtin_amdgcn_s_setprio(0);

    float* pdst = pb2b + kt*64;
#pragma unroll
    for (int j = 0; j < 8; ++j) {
      const int row = j*16 + prow;
      us4 pv = *(const us4*)&Pc[row*72 + pcol];
      f32x4 pf; pf[0] = bf2f(pv.x); pf[1] = bf2f(pv.y); pf[2] = bf2f(pv.z); pf[3] = bf2f(pv.w);
      __builtin_nontemporal_store(pf, (f32x4*)(pdst + (size_t)row*2048 + pcol));
    }
  }

  // ---- tile-b O epilogue ----
  __syncthreads();
  if (wc == 1) {
#pragma unroll
    for (int fm = 0; fm < 4; ++fm)
#pragma unroll
      for (int fd = 0; fd < 4; ++fd)
#pragma unroll
        for (int r = 0; r < 4; ++r)
          Ored[wr*4096 + (fm*16 + lg*4 + r)*64 + fd*16 + ll] = o[fm][fd][r];
  }
  __syncthreads();
  if (wc == 0) {
    const int b_ = hb & 3, h = hb >> 2;
#pragma unroll
    for (int fm = 0; fm < 4; ++fm)
#pragma unroll
      for (int fd = 0; fd < 4; ++fd)
#pragma unroll
        for (int r = 0; r < 4; ++r) {
          const int qrow = fm*16 + lg*4 + r;
          const int d = fd*16 + ll;
          float val = o[fm][fd][r] + Ored[wr*4096 + qrow*64 + d];
          const int mg = b_*2048 + qt_b*128 + wr*64 + qrow;
          attn_o[(size_t)mg*1024 + h*64 + d] = f2bf(val);
        }
  }
}

// ---------------- kernel 4: output projection (2-phase dbuf, LDS-coalesced epilogue) ----------------
__global__ __launch_bounds__(256, 2) void outproj_gemm(
    const unsigned short* __restrict__ Ain, const unsigned short* __restrict__ Wob,
    const float* __restrict__ bo, const float* __restrict__ qres, float* __restrict__ preLN)
{
  const int flat = blockIdx.x + (blockIdx.y << 6);
  const int xcd = flat & 7, ii = flat >> 3;
  const int m0 = (xcd * 8 + (ii & 7)) * 128;
  const int n0 = (ii >> 3) * 128;

  const int tid = threadIdx.x, lane = tid & 63, w = tid >> 6;
  const int wr = w >> 1, wc = w & 1;
  const int lg = lane >> 4, ll = lane & 15;

  __shared__ __align__(16) char smem_o[33792];
  unsigned short* As = (unsigned short*)smem_o;
  unsigned short* Bs = (unsigned short*)(smem_o + 16384);
  float* Tf = (float*)smem_o;                        // epilogue overlay [64][132] f32

  f32x4 acc[4][4] = {};

  const char* gA = (const char*)Ain + ((size_t)(m0 + w*32 + (lane >> 2)) * 1024) * 2 + (lane & 3) * 16;
  const char* gB = (const char*)Wob + ((size_t)(n0 + w*32 + (lane >> 2)) * 1024) * 2 + (lane & 3) * 16;

  STAGE_G(0);
  __syncthreads();

  for (int k0 = 0; k0 < 1024; k0 += 32) {
    const int cur = (k0 >> 5) & 1;
    if (k0 < 992) STAGE_G(cur ^ 1);
    const unsigned short* Ac = As + cur * 4096;
    const unsigned short* Bc = Bs + cur * 4096;
    bf16x8 xa[4], wb[4];
    const int kc = lg * 8;
#pragma unroll
    for (int f = 0; f < 4; ++f) xa[f] = *(const bf16x8*)&Ac[(wr*64 + f*16 + ll)*32 + kc];
#pragma unroll
    for (int f = 0; f < 4; ++f) wb[f] = *(const bf16x8*)&Bc[(wc*64 + f*16 + ll)*32 + kc];
#pragma unroll
    for (int fn = 0; fn < 4; ++fn)
#pragma unroll
      for (int fm = 0; fm < 4; ++fm)
        acc[fn][fm] = __builtin_amdgcn_mfma_f32_16x16x32_bf16(wb[fn], xa[fm], acc[fn][fm], 0, 0, 0);
    __syncthreads();
  }

#pragma unroll
  for (int half = 0; half < 2; ++half) {
    __syncthreads();
    if (wr == half) {
#pragma unroll
      for (int fn = 0; fn < 4; ++fn) {
        const int n_l = wc*64 + fn*16 + lg*4;
        const float4 b4 = *(const float4*)&bo[n0 + n_l];
#pragma unroll
        for (int fm = 0; fm < 4; ++fm) {
          f32x4 y;
          y[0] = acc[fn][fm][0] + b4.x;
          y[1] = acc[fn][fm][1] + b4.y;
          y[2] = acc[fn][fm][2] + b4.z;
          y[3] = acc[fn][fm][3] + b4.w;
          *(f32x4*)&Tf[(fm*16 + ll)*132 + n_l] = y;
        }
      }
    }
    __syncthreads();
    const int r_ = tid >> 5, c_ = (tid & 31) * 4;
#pragma unroll
    for (int it = 0; it < 8; ++it) {
      const int ml = it*8 + r_;
      f32x4 v = *(const f32x4*)&Tf[ml*132 + c_];
      const size_t idxp = (size_t)(m0 + half*64 + ml)*1024 + n0 + c_;
      const float4 r4 = *(const float4*)&qres[idxp];
      v[0] += r4.x; v[1] += r4.y; v[2] += r4.z; v[3] += r4.w;
      *(f32x4*)&preLN[idxp] = v;
    }
  }
}

// ---------------- kernel 5: LayerNorm ----------------
__global__ __launch_bounds__(256) void ln_kernel(
    const float* __restrict__ x, const float* __restrict__ gamma,
    const float* __restrict__ beta, float* __restrict__ out)
{
  const int row = blockIdx.x, tid = threadIdx.x;
  const float4 xv = ((const float4*)(x + (size_t)row * 1024))[tid];
  float s = xv.x + xv.y + xv.z + xv.w;
  float ss = xv.x*xv.x + xv.y*xv.y + xv.z*xv.z + xv.w*xv.w;
#pragma unroll
  for (int m = 1; m < 64; m <<= 1) { s += __shfl_xor(s, m); ss += __shfl_xor(ss, m); }
  __shared__ float red[8];
  if ((tid & 63) == 0) { red[(tid >> 6)*2] = s; red[(tid >> 6)*2 + 1] = ss; }
  __syncthreads();
  s  = red[0] + red[2] + red[4] + red[6];
  ss = red[1] + red[3] + red[5] + red[7];
  const float mu = s * (1.0f/1024.0f);
  const float var = ss * (1.0f/1024.0f) - mu*mu;
  const float rstd = rsqrtf(var + 1e-5f);
  const float4 g  = ((const float4*)gamma)[tid];
  const float4 be = ((const float4*)beta)[tid];
  float4 y;
  y.x = (xv.x - mu)*rstd*g.x + be.x;
  y.y = (xv.y - mu)*rstd*g.y + be.y;
  y.z = (xv.z - mu)*rstd*g.z + be.z;
  y.w = (xv.w - mu)*rstd*g.w + be.w;
  ((float4*)(out + (size_t)row * 1024))[tid] = y;
}

// ---------------- launch ----------------
extern "C" void kernel_launch(void* const* d_in, const int* in_sizes, int n_in,
                              void* d_out, int out_size, void* d_ws, size_t ws_size,
                              hipStream_t stream) {
  const float* q     = (const float*)d_in[0];
  const float* k     = (const float*)d_in[1];
  const float* v     = (const float*)d_in[2];
  const float* Wq    = (const float*)d_in[3];
  const float* bq    = (const float*)d_in[4];
  const float* Wk    = (const float*)d_in[5];
  const float* bk    = (const float*)d_in[6];
  const float* Wv    = (const float*)d_in[7];
  const float* bv    = (const float*)d_in[8];
  const float* Wo    = (const float*)d_in[9];
  const float* bo    = (const float*)d_in[10];
  const float* gamma = (const float*)d_in[11];
  const float* beta  = (const float*)d_in[12];

  float* out   = (float*)d_out;
  float* probs = out + 8388608;       // attn_flat region: [64][2048][2048] f32

  char* ws = (char*)d_ws;
  unsigned short* qb  = (unsigned short*)(ws);
  unsigned short* kb  = (unsigned short*)(ws + 16777216);
  unsigned short* vb  = (unsigned short*)(ws + 33554432);
  unsigned short* wqb = (unsigned short*)(ws + 50331648);
  unsigned short* wkb = (unsigned short*)(ws + 52428800);
  unsigned short* wvb = (unsigned short*)(ws + 54525952);
  unsigned short* wob = (unsigned short*)(ws + 56623104);
  unsigned short* qh  = (unsigned short*)(ws + 58720256);  // [64 slabs][2048][64]
  unsigned short* kh  = (unsigned short*)(ws + 75497472);
  unsigned short* vt  = (unsigned short*)(ws + 92274688);  // [64 slabs][64][2048]
  float* preLN = (float*)(ws);                 // overlays qb+kb (dead by then)
  unsigned short* attn_o = vb;                 // overlays vb (dead by then)

  convert_all<<<28672, 256, 0, stream>>>(q, k, v, Wq, Wk, Wv, Wo,
                                         qb, kb, vb, wqb, wkb, wvb, wob);

  dim3 g1(64, 8, 3);
  qkv_gemm<<<g1, 256, 0, stream>>>(qb, kb, vb, wqb, wkb, wvb, bq, bk, bv, qh, kh, vt);

  attn_kernel<<<512, 256, 0, stream>>>(qh, kh, vt, probs, attn_o);

  dim3 g3(64, 8);
  outproj_gemm<<<g3, 256, 0, stream>>>(attn_o, wob, bo, q, preLN);

  ln_kernel<<<8192, 256, 0, stream>>>(preLN, gamma, beta, out);
}

// Round 12
// 435.227 us; speedup vs baseline: 1.0298x; 1.0298x over previous
//
#include <hip/hip_runtime.h>
#include <stdint.h>

typedef short bf16x8 __attribute__((ext_vector_type(8)));
typedef float f32x4 __attribute__((ext_vector_type(4)));
typedef unsigned short us4 __attribute__((ext_vector_type(4)));
typedef unsigned short us8 __attribute__((ext_vector_type(8)));
typedef unsigned uint2v __attribute__((ext_vector_type(2)));

#define SCL 0.18033688011112042f  /* log2(e)/sqrt(64) */

__device__ __forceinline__ unsigned short f2bf(float f) {
  union { float f; unsigned u; } v; v.f = f;
  unsigned r = v.u + 0x7fffu + ((v.u >> 16) & 1u);
  return (unsigned short)(r >> 16);
}

__device__ __forceinline__ unsigned cvtpk(float lo, float hi) {
  unsigned r;
  asm("v_cvt_pk_bf16_f32 %0, %1, %2" : "=v"(r) : "v"(lo), "v"(hi));
  return r;
}

__device__ __forceinline__ float bf2f(unsigned short h) {
  union { unsigned u; float f; } v; v.u = ((unsigned)h) << 16; return v.f;
}

#define GL2LDS(g, l) __builtin_amdgcn_global_load_lds( \
    (const __attribute__((address_space(1))) void*)(g), \
    (__attribute__((address_space(3))) void*)(l), 16, 0, 0)

// ---------------- kernel 1: f32 -> bf16 conversion ----------------
__global__ __launch_bounds__(256) void convert_all(
    const float* __restrict__ q, const float* __restrict__ k, const float* __restrict__ v,
    const float* __restrict__ wq, const float* __restrict__ wk, const float* __restrict__ wv,
    const float* __restrict__ wo,
    unsigned short* __restrict__ qb, unsigned short* __restrict__ kb, unsigned short* __restrict__ vb,
    unsigned short* __restrict__ wqb, unsigned short* __restrict__ wkb, unsigned short* __restrict__ wvb,
    unsigned short* __restrict__ wob)
{
  const long NB = 8388608, NW = 1048576;
  long i = ((long)blockIdx.x * 256 + threadIdx.x) * 4;
  if (i >= 3*NB + 4*NW) return;
  const float* src; unsigned short* dst; long off;
  if (i < NB)              { src = q;  dst = qb;  off = i; }
  else if (i < 2*NB)       { src = k;  dst = kb;  off = i - NB; }
  else if (i < 3*NB)       { src = v;  dst = vb;  off = i - 2*NB; }
  else if (i < 3*NB+NW)    { src = wq; dst = wqb; off = i - 3*NB; }
  else if (i < 3*NB+2*NW)  { src = wk; dst = wkb; off = i - 3*NB - NW; }
  else if (i < 3*NB+3*NW)  { src = wv; dst = wvb; off = i - 3*NB - 2*NW; }
  else                     { src = wo; dst = wob; off = i - 3*NB - 3*NW; }
  float4 x = *(const float4*)(src + off);
  us4 o; o.x = f2bf(x.x); o.y = f2bf(x.y); o.z = f2bf(x.z); o.w = f2bf(x.w);
  *(us4*)(dst + off) = o;
}

// ---------------- kernel 2: QKV projection GEMM (z-loop for L2 phasing) ----------------
// z=0 -> qh (PRE-SCALED by SCL), z=1 -> kh, z=2 -> vt (transposed per head)
__global__ __launch_bounds__(256, 2) void qkv_gemm(
    const unsigned short* __restrict__ qb, const unsigned short* __restrict__ kb,
    const unsigned short* __restrict__ vb,
    const unsigned short* __restrict__ wqb, const unsigned short* __restrict__ wkb,
    const unsigned short* __restrict__ wvb,
    const float* __restrict__ bq, const float* __restrict__ bk, const float* __restrict__ bv,
    unsigned short* __restrict__ qh, unsigned short* __restrict__ kh,
    unsigned short* __restrict__ vt)
{
  const int flat = blockIdx.x + (blockIdx.y << 6);
  const int xcd = flat & 7, ii = flat >> 3;
  const int m0 = (xcd * 8 + (ii & 7)) * 128;
  const int n0 = (ii >> 3) * 128;

  const int tid = threadIdx.x, lane = tid & 63, w = tid >> 6;
  const int wr = w >> 1, wc = w & 1;
  const int lg = lane >> 4, ll = lane & 15;

  __shared__ __align__(16) char smem_q[32768];
  unsigned short* As = (unsigned short*)smem_q;             // [2][128][32]
  unsigned short* Bs = (unsigned short*)(smem_q + 16384);   // [2][128][32]
  unsigned short* T  = (unsigned short*)smem_q;             // epilogue overlay [64][130]

  const unsigned short* Xs_[3] = {qb, kb, vb};
  const unsigned short* Ws_[3] = {wqb, wkb, wvb};
  const float* bias_[3] = {bq, bk, bv};

#define STAGE_G(buf) do { \
    char* lA_ = (char*)As + (buf)*8192 + w*2048; \
    char* lB_ = (char*)Bs + (buf)*8192 + w*2048; \
    GL2LDS(gA, lA_); GL2LDS(gA + 32768, lA_ + 1024); \
    GL2LDS(gB, lB_); GL2LDS(gB + 32768, lB_ + 1024); \
    gA += 64; gB += 64; } while (0)

  for (int z = 0; z < 3; ++z) {
    const unsigned short* X = Xs_[z];
    const unsigned short* W = Ws_[z];
    const float* bias = bias_[z];
    unsigned short* dqh = (z == 0) ? qh : kh;
    const float sc = (z == 0) ? SCL : 1.0f;

    f32x4 acc[4][4] = {};

    const char* gA = (const char*)X + ((size_t)(m0 + w*32 + (lane >> 2)) * 1024) * 2 + (lane & 3) * 16;
    const char* gB = (const char*)W + ((size_t)(n0 + w*32 + (lane >> 2)) * 1024) * 2 + (lane & 3) * 16;

    STAGE_G(0);
    __syncthreads();

    for (int k0 = 0; k0 < 1024; k0 += 32) {
      const int cur = (k0 >> 5) & 1;
      if (k0 < 992) STAGE_G(cur ^ 1);
      const unsigned short* Ac = As + cur * 4096;
      const unsigned short* Bc = Bs + cur * 4096;
      bf16x8 xa[4], wb[4];
      const int kc = lg * 8;
#pragma unroll
      for (int f = 0; f < 4; ++f) xa[f] = *(const bf16x8*)&Ac[(wr*64 + f*16 + ll)*32 + kc];
#pragma unroll
      for (int f = 0; f < 4; ++f) wb[f] = *(const bf16x8*)&Bc[(wc*64 + f*16 + ll)*32 + kc];
      if (z < 2) {
#pragma unroll
        for (int fn = 0; fn < 4; ++fn)
#pragma unroll
          for (int fm = 0; fm < 4; ++fm)
            acc[fn][fm] = __builtin_amdgcn_mfma_f32_16x16x32_bf16(wb[fn], xa[fm], acc[fn][fm], 0, 0, 0);
      } else {
#pragma unroll
        for (int fm = 0; fm < 4; ++fm)
#pragma unroll
          for (int fn = 0; fn < 4; ++fn)
            acc[fm][fn] = __builtin_amdgcn_mfma_f32_16x16x32_bf16(xa[fm], wb[fn], acc[fm][fn], 0, 0, 0);
      }
      __syncthreads();
    }

    const int b_ = m0 >> 11;
    if (z < 2) {
#pragma unroll
      for (int half = 0; half < 2; ++half) {
        __syncthreads();
        if (wr == half) {
#pragma unroll
          for (int fn = 0; fn < 4; ++fn) {
            const int n_l = wc*64 + fn*16 + lg*4;
            const float4 b4 = *(const float4*)&bias[n0 + n_l];
#pragma unroll
            for (int fm = 0; fm < 4; ++fm) {
              us4 pk;
              pk.x = f2bf((acc[fn][fm][0] + b4.x) * sc);
              pk.y = f2bf((acc[fn][fm][1] + b4.y) * sc);
              pk.z = f2bf((acc[fn][fm][2] + b4.z) * sc);
              pk.w = f2bf((acc[fn][fm][3] + b4.w) * sc);
              *(us4*)&T[(fm*16 + ll)*130 + n_l] = pk;
            }
          }
        }
        __syncthreads();
        const int seg = tid >> 3, off = (tid & 7) * 8;
#pragma unroll
        for (int it = 0; it < 4; ++it) {
          const int s = it*32 + seg;
          const int ml = s >> 1, nh = (s & 1) << 6;
          us8 v = *(const us8*)&T[ml*130 + nh + off];
          const int m_g = m0 + half*64 + ml;
          const int l_ = m_g & 2047;
          const int h = (n0 + nh) >> 6;
          *(us8*)&dqh[((size_t)(h*4 + b_)*2048 + l_)*64 + off] = v;
        }
      }
    } else {
#pragma unroll
      for (int half = 0; half < 2; ++half) {
        __syncthreads();
        if (wc == half) {
#pragma unroll
          for (int fn = 0; fn < 4; ++fn) {
            const float bias_n = bias[n0 + half*64 + fn*16 + ll];
#pragma unroll
            for (int fm = 0; fm < 4; ++fm) {
              us4 pk;
              pk.x = f2bf(acc[fm][fn][0] + bias_n);
              pk.y = f2bf(acc[fm][fn][1] + bias_n);
              pk.z = f2bf(acc[fm][fn][2] + bias_n);
              pk.w = f2bf(acc[fm][fn][3] + bias_n);
              *(us4*)&T[(fn*16 + ll)*130 + wr*64 + fm*16 + lg*4] = pk;
            }
          }
        }
        __syncthreads();
        const int row = tid >> 4, mc = (tid & 15) * 8;
#pragma unroll
        for (int it = 0; it < 4; ++it) {
          const int rr = it*16 + row;
          us8 v = *(const us8*)&T[rr*130 + mc];
          const int n_g = n0 + half*64 + rr;
          const int h = n_g >> 6, dkk = n_g & 63;
          const int l_ = (m0 + mc) & 2047;
          *(us8*)&vt[((size_t)(h*4 + b_)*64 + dkk)*2048 + l_] = v;
        }
      }
    }
    __syncthreads();   // T dead before next z's STAGE overwrites As/Bs
  }
}

// ---------------- kernel 3: attention v9 (R10 base; PV hoisted before barrier) ----------------
__global__ __launch_bounds__(256, 2) void attn_kernel(
    const unsigned short* __restrict__ qh, const unsigned short* __restrict__ kh,
    const unsigned short* __restrict__ vt, float* __restrict__ probs,
    unsigned short* __restrict__ attn_o)
{
  const int bid = blockIdx.x;
  const int xcd = bid & 7;
  const int idx = bid >> 3;
  const int hb  = xcd * 8 + (idx & 7);
  const int qt  = idx >> 3;

  const int tid = threadIdx.x, lane = tid & 63, w = tid >> 6;
  const int wr = w >> 1, wc = w & 1;
  const int lg = lane >> 4, ll = lane & 15;

  __shared__ __align__(16) char smem[38400];
  unsigned short* Pb = (unsigned short*)smem;        // [2][128][72] bf16 (36864 B)
  float* rs   = (float*)(smem + 36864);              // [2][128]
  float* invl = (float*)(smem + 37888);              // [128]
  float* Ored = (float*)smem;                        // epilogue overlay [2][64][64]

  const size_t slab = (size_t)hb << 17;

  bf16x8 qf[4][2];
#pragma unroll
  for (int fq = 0; fq < 4; ++fq)
#pragma unroll
    for (int dh = 0; dh < 2; ++dh)
      qf[fq][dh] = *(const bf16x8*)&qh[slab + (size_t)(qt*128 + wr*64 + fq*16 + ll)*64 + dh*32 + lg*8];

  const unsigned short* Kf = kh + slab + (size_t)(wc*32 + ll)*64 + lg*8;
  const unsigned short* Vf = vt + slab + (size_t)ll*2048 + wc*32 + lg*8;

  // ---- pass 1: row sums of exp2(s) ----
  float rsum[4] = {0.f, 0.f, 0.f, 0.f};
  for (int kt = 0; kt < 32; ++kt) {
    bf16x8 ka[2][2];
#pragma unroll
    for (int fk = 0; fk < 2; ++fk)
#pragma unroll
      for (int dh = 0; dh < 2; ++dh)
        ka[fk][dh] = *(const bf16x8*)(Kf + kt*4096 + fk*1024 + dh*32);
    f32x4 s[2][4] = {};
    __builtin_amdgcn_s_setprio(1);
#pragma unroll
    for (int dh = 0; dh < 2; ++dh)
#pragma unroll
      for (int fk = 0; fk < 2; ++fk)
#pragma unroll
        for (int fq = 0; fq < 4; ++fq)
          s[fk][fq] = __builtin_amdgcn_mfma_f32_16x16x32_bf16(ka[fk][dh], qf[fq][dh], s[fk][fq], 0, 0, 0);
    __builtin_amdgcn_s_setprio(0);
#pragma unroll
    for (int fk = 0; fk < 2; ++fk)
#pragma unroll
      for (int fq = 0; fq < 4; ++fq)
#pragma unroll
        for (int r = 0; r < 4; ++r)
          rsum[fq] += exp2f(s[fk][fq][r]);
  }

#pragma unroll
  for (int fq = 0; fq < 4; ++fq) {
    float t = rsum[fq];
    t += __shfl_xor(t, 16);
    t += __shfl_xor(t, 32);
    rsum[fq] = t;
  }
  if (lg == 0) {
#pragma unroll
    for (int fq = 0; fq < 4; ++fq)
      rs[wc*128 + wr*64 + fq*16 + ll] = rsum[fq];
  }
  __syncthreads();
  if (tid < 128) invl[tid] = 1.0f / (rs[tid] + rs[128 + tid]);
  __syncthreads();
  float inv_r[4];
#pragma unroll
  for (int fq = 0; fq < 4; ++fq) inv_r[fq] = invl[wr*64 + fq*16 + ll];

  // ---- pass 2: dbuf P-tile; PV before barrier (same-wave RAW), store after ----
  f32x4 o[4][4] = {};
  float* pb2 = probs + ((size_t)hb << 22) + (size_t)(qt*128) * 2048;
  const int prow = tid >> 4, pcol = (tid & 15) * 4;

  auto body = [&](bf16x8 (&ka)[2][2], bf16x8 (&kan)[2][2], int kt) {
    unsigned short* Pc = Pb + (kt & 1) * 9216;  // [128][72] half
    bf16x8 vb[4];
#pragma unroll
    for (int f = 0; f < 4; ++f)
      vb[f] = *(const bf16x8*)(Vf + f*32768 + kt*64);

    f32x4 s[2][4] = {};
    __builtin_amdgcn_s_setprio(1);
#pragma unroll
    for (int dh = 0; dh < 2; ++dh)
#pragma unroll
      for (int fk = 0; fk < 2; ++fk)
#pragma unroll
        for (int fq = 0; fq < 4; ++fq)
          s[fk][fq] = __builtin_amdgcn_mfma_f32_16x16x32_bf16(ka[fk][dh], qf[fq][dh], s[fk][fq], 0, 0, 0);
    __builtin_amdgcn_s_setprio(0);

    if (kt + 1 < 32) {
#pragma unroll
      for (int fk = 0; fk < 2; ++fk)
#pragma unroll
        for (int dh = 0; dh < 2; ++dh)
          kan[fk][dh] = *(const bf16x8*)(Kf + (kt+1)*4096 + fk*1024 + dh*32);
    }

#pragma unroll
    for (int fk = 0; fk < 2; ++fk)
#pragma unroll
      for (int fq = 0; fq < 4; ++fq) {
        float p0 = exp2f(s[fk][fq][0]) * inv_r[fq];
        float p1 = exp2f(s[fk][fq][1]) * inv_r[fq];
        float p2 = exp2f(s[fk][fq][2]) * inv_r[fq];
        float p3 = exp2f(s[fk][fq][3]) * inv_r[fq];
        uint2v u; u.x = cvtpk(p0, p1); u.y = cvtpk(p2, p3);
        *(uint2v*)&Pc[(wr*64 + fq*16 + ll)*72 + wc*32 + fk*16 + lg*4] = u;
      }

    // PV: reads own wave's quadrant only — no barrier needed (lgkmcnt orders RAW)
    bf16x8 pa[4];
#pragma unroll
    for (int fm = 0; fm < 4; ++fm)
      pa[fm] = *(const bf16x8*)&Pc[(wr*64 + fm*16 + ll)*72 + wc*32 + lg*8];
    __builtin_amdgcn_s_setprio(1);
#pragma unroll
    for (int fm = 0; fm < 4; ++fm)
#pragma unroll
      for (int fd = 0; fd < 4; ++fd)
        o[fm][fd] = __builtin_amdgcn_mfma_f32_16x16x32_bf16(pa[fm], vb[fd], o[fm][fd], 0, 0, 0);
    __builtin_amdgcn_s_setprio(0);

    __syncthreads();   // all waves' quadrants visible for the transposed store

    float* pdst = pb2 + kt*64;
#pragma unroll
    for (int j = 0; j < 8; ++j) {
      const int row = j*16 + prow;
      us4 pv = *(const us4*)&Pc[row*72 + pcol];
      f32x4 pf; pf[0] = bf2f(pv.x); pf[1] = bf2f(pv.y); pf[2] = bf2f(pv.z); pf[3] = bf2f(pv.w);
      __builtin_nontemporal_store(pf, (f32x4*)(pdst + (size_t)row*2048 + pcol));
    }
  };

  bf16x8 kaA[2][2], kaB[2][2];
#pragma unroll
  for (int fk = 0; fk < 2; ++fk)
#pragma unroll
    for (int dh = 0; dh < 2; ++dh)
      kaA[fk][dh] = *(const bf16x8*)(Kf + fk*1024 + dh*32);
  for (int kt = 0; kt < 32; kt += 2) {
    body(kaA, kaB, kt);
    body(kaB, kaA, kt + 1);
  }

  // ---- cross-wave (k-split) O reduction, write attn output ----
  __syncthreads();
  if (wc == 1) {
#pragma unroll
    for (int fm = 0; fm < 4; ++fm)
#pragma unroll
      for (int fd = 0; fd < 4; ++fd)
#pragma unroll
        for (int r = 0; r < 4; ++r)
          Ored[wr*4096 + (fm*16 + lg*4 + r)*64 + fd*16 + ll] = o[fm][fd][r];
  }
  __syncthreads();
  if (wc == 0) {
    const int b_ = hb & 3, h = hb >> 2;
#pragma unroll
    for (int fm = 0; fm < 4; ++fm)
#pragma unroll
      for (int fd = 0; fd < 4; ++fd)
#pragma unroll
        for (int r = 0; r < 4; ++r) {
          const int qrow = fm*16 + lg*4 + r;
          const int d = fd*16 + ll;
          float val = o[fm][fd][r] + Ored[wr*4096 + qrow*64 + d];
          const int mg = b_*2048 + qt*128 + wr*64 + qrow;
          attn_o[(size_t)mg*1024 + h*64 + d] = f2bf(val);
        }
  }
}

// ---------------- kernel 4: output projection (2-phase dbuf, LDS-coalesced epilogue) ----------------
__global__ __launch_bounds__(256, 2) void outproj_gemm(
    const unsigned short* __restrict__ Ain, const unsigned short* __restrict__ Wob,
    const float* __restrict__ bo, const float* __restrict__ qres, float* __restrict__ preLN)
{
  const int flat = blockIdx.x + (blockIdx.y << 6);
  const int xcd = flat & 7, ii = flat >> 3;
  const int m0 = (xcd * 8 + (ii & 7)) * 128;
  const int n0 = (ii >> 3) * 128;

  const int tid = threadIdx.x, lane = tid & 63, w = tid >> 6;
  const int wr = w >> 1, wc = w & 1;
  const int lg = lane >> 4, ll = lane & 15;

  __shared__ __align__(16) char smem_o[33792];
  unsigned short* As = (unsigned short*)smem_o;
  unsigned short* Bs = (unsigned short*)(smem_o + 16384);
  float* Tf = (float*)smem_o;                        // epilogue overlay [64][132] f32

  f32x4 acc[4][4] = {};

  const char* gA = (const char*)Ain + ((size_t)(m0 + w*32 + (lane >> 2)) * 1024) * 2 + (lane & 3) * 16;
  const char* gB = (const char*)Wob + ((size_t)(n0 + w*32 + (lane >> 2)) * 1024) * 2 + (lane & 3) * 16;

  STAGE_G(0);
  __syncthreads();

  for (int k0 = 0; k0 < 1024; k0 += 32) {
    const int cur = (k0 >> 5) & 1;
    if (k0 < 992) STAGE_G(cur ^ 1);
    const unsigned short* Ac = As + cur * 4096;
    const unsigned short* Bc = Bs + cur * 4096;
    bf16x8 xa[4], wb[4];
    const int kc = lg * 8;
#pragma unroll
    for (int f = 0; f < 4; ++f) xa[f] = *(const bf16x8*)&Ac[(wr*64 + f*16 + ll)*32 + kc];
#pragma unroll
    for (int f = 0; f < 4; ++f) wb[f] = *(const bf16x8*)&Bc[(wc*64 + f*16 + ll)*32 + kc];
#pragma unroll
    for (int fn = 0; fn < 4; ++fn)
#pragma unroll
      for (int fm = 0; fm < 4; ++fm)
        acc[fn][fm] = __builtin_amdgcn_mfma_f32_16x16x32_bf16(wb[fn], xa[fm], acc[fn][fm], 0, 0, 0);
    __syncthreads();
  }

#pragma unroll
  for (int half = 0; half < 2; ++half) {
    __syncthreads();
    if (wr == half) {
#pragma unroll
      for (int fn = 0; fn < 4; ++fn) {
        const int n_l = wc*64 + fn*16 + lg*4;
        const float4 b4 = *(const float4*)&bo[n0 + n_l];
#pragma unroll
        for (int fm = 0; fm < 4; ++fm) {
          f32x4 y;
          y[0] = acc[fn][fm][0] + b4.x;
          y[1] = acc[fn][fm][1] + b4.y;
          y[2] = acc[fn][fm][2] + b4.z;
          y[3] = acc[fn][fm][3] + b4.w;
          *(f32x4*)&Tf[(fm*16 + ll)*132 + n_l] = y;
        }
      }
    }
    __syncthreads();
    const int r_ = tid >> 5, c_ = (tid & 31) * 4;
#pragma unroll
    for (int it = 0; it < 8; ++it) {
      const int ml = it*8 + r_;
      f32x4 v = *(const f32x4*)&Tf[ml*132 + c_];
      const size_t idxp = (size_t)(m0 + half*64 + ml)*1024 + n0 + c_;
      const float4 r4 = *(const float4*)&qres[idxp];
      v[0] += r4.x; v[1] += r4.y; v[2] += r4.z; v[3] += r4.w;
      *(f32x4*)&preLN[idxp] = v;
    }
  }
}

// ---------------- kernel 5: LayerNorm ----------------
__global__ __launch_bounds__(256) void ln_kernel(
    const float* __restrict__ x, const float* __restrict__ gamma,
    const float* __restrict__ beta, float* __restrict__ out)
{
  const int row = blockIdx.x, tid = threadIdx.x;
  const float4 xv = ((const float4*)(x + (size_t)row * 1024))[tid];
  float s = xv.x + xv.y + xv.z + xv.w;
  float ss = xv.x*xv.x + xv.y*xv.y + xv.z*xv.z + xv.w*xv.w;
#pragma unroll
  for (int m = 1; m < 64; m <<= 1) { s += __shfl_xor(s, m); ss += __shfl_xor(ss, m); }
  __shared__ float red[8];
  if ((tid & 63) == 0) { red[(tid >> 6)*2] = s; red[(tid >> 6)*2 + 1] = ss; }
  __syncthreads();
  s  = red[0] + red[2] + red[4] + red[6];
  ss = red[1] + red[3] + red[5] + red[7];
  const float mu = s * (1.0f/1024.0f);
  const float var = ss * (1.0f/1024.0f) - mu*mu;
  const float rstd = rsqrtf(var + 1e-5f);
  const float4 g  = ((const float4*)gamma)[tid];
  const float4 be = ((const float4*)beta)[tid];
  float4 y;
  y.x = (xv.x - mu)*rstd*g.x + be.x;
  y.y = (xv.y - mu)*rstd*g.y + be.y;
  y.z = (xv.z - mu)*rstd*g.z + be.z;
  y.w = (xv.w - mu)*rstd*g.w + be.w;
  ((float4*)(out + (size_t)row * 1024))[tid] = y;
}

// ---------------- launch ----------------
extern "C" void kernel_launch(void* const* d_in, const int* in_sizes, int n_in,
                              void* d_out, int out_size, void* d_ws, size_t ws_size,
                              hipStream_t stream) {
  const float* q     = (const float*)d_in[0];
  const float* k     = (const float*)d_in[1];
  const float* v     = (const float*)d_in[2];
  const float* Wq    = (const float*)d_in[3];
  const float* bq    = (const float*)d_in[4];
  const float* Wk    = (const float*)d_in[5];
  const float* bk    = (const float*)d_in[6];
  const float* Wv    = (const float*)d_in[7];
  const float* bv    = (const float*)d_in[8];
  const float* Wo    = (const float*)d_in[9];
  const float* bo    = (const float*)d_in[10];
  const float* gamma = (const float*)d_in[11];
  const float* beta  = (const float*)d_in[12];

  float* out   = (float*)d_out;
  float* probs = out + 8388608;       // attn_flat region: [64][2048][2048] f32

  char* ws = (char*)d_ws;
  unsigned short* qb  = (unsigned short*)(ws);
  unsigned short* kb  = (unsigned short*)(ws + 16777216);
  unsigned short* vb  = (unsigned short*)(ws + 33554432);
  unsigned short* wqb = (unsigned short*)(ws + 50331648);
  unsigned short* wkb = (unsigned short*)(ws + 52428800);
  unsigned short* wvb = (unsigned short*)(ws + 54525952);
  unsigned short* wob = (unsigned short*)(ws + 56623104);
  unsigned short* qh  = (unsigned short*)(ws + 58720256);  // [64 slabs][2048][64]
  unsigned short* kh  = (unsigned short*)(ws + 75497472);
  unsigned short* vt  = (unsigned short*)(ws + 92274688);  // [64 slabs][64][2048]
  float* preLN = (float*)(ws);                 // overlays qb+kb (dead by then)
  unsigned short* attn_o = vb;                 // overlays vb (dead by then)

  convert_all<<<28672, 256, 0, stream>>>(q, k, v, Wq, Wk, Wv, Wo,
                                         qb, kb, vb, wqb, wkb, wvb, wob);

  dim3 g1(64, 8);
  qkv_gemm<<<g1, 256, 0, stream>>>(qb, kb, vb, wqb, wkb, wvb, bq, bk, bv, qh, kh, vt);

  attn_kernel<<<1024, 256, 0, stream>>>(qh, kh, vt, probs, attn_o);

  dim3 g3(64, 8);
  outproj_gemm<<<g3, 256, 0, stream>>>(attn_o, wob, bo, q, preLN);

  ln_kernel<<<8192, 256, 0, stream>>>(preLN, gamma, beta, out);
}